// Round 11
// baseline (97.814 us; speedup 1.0000x reference)
//
#include <hip/hip_runtime.h>

// Additive (Bahdanau) attention, fp32 in/out.
// B=2, L=512, S=512, H=8, E=32, D=64.
// scores[b,h,l,s] = sum_e tanh(q[b,l,h,e] + k[b,s,h,e]) * v[e]  (+ masks)
// A = softmax_s(scores); out[b,l,h,d] = sum_s A * values[b,s,h,d]
//
// tanh(x) = 1 - 2/(exp2(SC*x)+1), SC = 2*log2(e);
// exp2(SC*(q+k)) = exp2(SC*q)*exp2(SC*k). Pair identity halves rcp count:
//   v0/q0 + v1/q1 = (v0*q1 + v1*q0) / (q0*q1),  q_i = 1 + eq_i*ek_i >= 1.
//
// R11: FULL OCCUPANCY push. R8-R10 showed main is latency-stall-bound with
// TLP capped at 4 waves/SIMD (LDS 40KB and grid 1024 both -> 4 blocks/CU).
// Now: 1 row/wave, 4 rows/block -> grid 2048; ek processed in two 16KB
// half-slabs through ONE LDS buffer (sAb 4KB aliases it after last read);
// e-split two-pass + SGPR eq (readfirstlane) + pair-rcp keep VGPR <= 64.
// => 8 blocks/CU, 32 waves/CU. 5 barriers, all overlap across blocks.

#define BB 2
#define LL 512
#define SS 512
#define HH 8
#define EE 32
#define DD 64

// d_ws layout (bytes):
//   [0, 512K)  ws_ekb : u32x4[B][H][e8:4][s:512]   bf16 pairs of exp2(SC*k)
//   [2M, 4M)   ws_eq  : float[B][L][H][E]          exp2(SC*q)
//   [4M, 5M)   ws_vtf : u32x4[B][H][dchunk:4][c:16][lane:64]  MFMA B-frags
#define WS_EK_OFF 0
#define WS_EQ_OFF (2u * 1024u * 1024u)
#define WS_VT_OFF (4u * 1024u * 1024u)

typedef __attribute__((ext_vector_type(8))) short bf16x8;
typedef __attribute__((ext_vector_type(4))) float f32x4;
typedef __attribute__((ext_vector_type(4))) unsigned u32x4;

__device__ __forceinline__ unsigned short f2bf(float f) {   // fp32->bf16 RNE
    unsigned u = __float_as_uint(f);
    u += 0x7FFFu + ((u >> 16) & 1u);
    return (unsigned short)(u >> 16);
}
__device__ __forceinline__ float fast_exp2(float x) {
#if __has_builtin(__builtin_amdgcn_exp2f)
    return __builtin_amdgcn_exp2f(x);
#else
    return exp2f(x);
#endif
}
__device__ __forceinline__ float fast_rcp(float x) {
    return __builtin_amdgcn_rcpf(x);
}
__device__ __forceinline__ float bcastf(float x) {   // force into SGPR
    return __int_as_float(__builtin_amdgcn_readfirstlane(__float_as_int(x)));
}

#define SCV 2.885390081777927f   // 2*log2(e)

// ---------------- prep kernel: 640 blocks x 256 (same as R10) ------------
__global__ __launch_bounds__(256) void prep_kernel(
    const float* __restrict__ q, const float* __restrict__ k,
    const float* __restrict__ vals, float* __restrict__ ws)
{
    unsigned gid = blockIdx.x * 256 + threadIdx.x;
    if (gid < 32768u) {
        // i = [b:1][h:3][e8:2][s:9]; entry = bf16(exp2(SC*k[b][s][h][8e8..+7]))
        unsigned i  = gid;
        unsigned s  = i & 511u;
        unsigned e8 = (i >> 9) & 3u;
        unsigned h  = (i >> 11) & 7u;
        unsigned b  = i >> 14;
        const float* kr = k + (((size_t)b * SS + s) * HH + h) * EE + e8 * 8;
        float4 k0 = *(const float4*)kr;
        float4 k1 = *(const float4*)(kr + 4);
        u32x4 pk;
        pk[0] = (unsigned)f2bf(fast_exp2(SCV * k0.x)) |
                ((unsigned)f2bf(fast_exp2(SCV * k0.y)) << 16);
        pk[1] = (unsigned)f2bf(fast_exp2(SCV * k0.z)) |
                ((unsigned)f2bf(fast_exp2(SCV * k0.w)) << 16);
        pk[2] = (unsigned)f2bf(fast_exp2(SCV * k1.x)) |
                ((unsigned)f2bf(fast_exp2(SCV * k1.y)) << 16);
        pk[3] = (unsigned)f2bf(fast_exp2(SCV * k1.z)) |
                ((unsigned)f2bf(fast_exp2(SCV * k1.w)) << 16);
        ((u32x4*)((char*)ws + WS_EK_OFF))[i] = pk;
    } else if (gid < 98304u) {
        unsigned i = gid - 32768u;   // eq: elementwise, q's linear layout
        float4 qv = ((const float4*)q)[i];
        float4 ev = make_float4(fast_exp2(SCV * qv.x), fast_exp2(SCV * qv.y),
                                fast_exp2(SCV * qv.z), fast_exp2(SCV * qv.w));
        ((float4*)(ws + WS_EQ_OFF / 4))[i] = ev;
    } else {
        // vtf: i = [b:1][h:3][dchunk:2][c:4][lane:6]
        // entry = B-frag (chunk c, lane): V[s=c*32+qd*8+j][d=dchunk*16+n]
        unsigned i      = gid - 98304u;
        unsigned lane   = i & 63u;
        unsigned c      = (i >> 6) & 15u;
        unsigned dchunk = (i >> 10) & 3u;
        unsigned h      = (i >> 12) & 7u;
        unsigned b      = i >> 15;
        unsigned qd = lane >> 4, n = lane & 15;
        unsigned d  = dchunk * 16 + n;
        unsigned s0 = c * 32 + qd * 8;
        const float* vb = vals + (((size_t)b * SS + s0) * HH + h) * DD + d;
        u32x4 pk;
        #pragma unroll
        for (int j2 = 0; j2 < 4; j2++) {
            float f0 = vb[(size_t)(2 * j2) * (HH * DD)];
            float f1 = vb[(size_t)(2 * j2 + 1) * (HH * DD)];
            pk[j2] = (unsigned)f2bf(f0) | ((unsigned)f2bf(f1) << 16);
        }
        ((u32x4*)((char*)ws + WS_VT_OFF))[i] = pk;
    }
}

// ---------------- main kernel: 2048 blocks x 256 ----------------
__global__ __launch_bounds__(256) void addattn_kernel(
    const u32x4* __restrict__ ws_ekb,   // bf16 ek slab images
    const float* __restrict__ ws_eqf,   // exp2(SC*q)
    const bf16x8* __restrict__ ws_vtf,  // pre-fragmented V (B-operand image)
    const float* __restrict__ vvec,     // (E)
    const float* __restrict__ mask,     // (L,S)
    const float* __restrict__ klen,     // (B,S)
    float* __restrict__ out)            // (B,L,H,D)
{
    // 16 KB: one s-half-slab of ek, [e8:4][sl:256] bf16. sAb (4 rows x 512
    // bf16 = 4 KB) aliases the front after the last sek read.
    __shared__ u32x4 sek[4][256];
    unsigned short* sAb = (unsigned short*)sek;

    const int tid  = threadIdx.x;
    const int w    = tid >> 6;
    const int lane = tid & 63;
    const int bh   = blockIdx.x >> 7;          // 16 (b,h) pairs
    const int lblk = blockIdx.x & 127;         // 128 l-blocks of 4 rows
    const int b    = bh >> 3;
    const int h    = bh & 7;
    const int l0   = lblk * 4;
    const int l    = l0 + w;                   // this wave's row

    const u32x4* slab = ws_ekb + (size_t)(b * HH + h) * (4 * 512);
    const float* eqbase = ws_eqf + (((size_t)b * LL + l) * HH + h) * EE;

    float sc[SS / 64];
    #pragma unroll
    for (int i = 0; i < SS / 64; i++) sc[i] = 0.f;

    for (int hs = 0; hs < 2; hs++) {           // two s-half-slabs
        if (hs) __syncthreads();               // all reads of half 0 done
        // stage 16 KB: thread t copies 4 entries (coalesced over sl)
        #pragma unroll
        for (int t = 0; t < 4; t++) {
            int idx = tid + t * 256;
            int e8  = idx >> 8;
            int sl  = idx & 255;
            sek[e8][sl] = slab[e8 * 512 + hs * 256 + sl];
        }
        __syncthreads();                       // staged

        for (int p = 0; p < 2; p++) {          // two e-halves (16 elems each)
            // eq / v2 for this e-half -> SGPRs (wave-uniform)
            float eqs[16], v2h[16];
            #pragma unroll
            for (int e = 0; e < 16; e += 4) {
                float4 t0 = *(const float4*)(eqbase + p * 16 + e);
                float4 tv = *(const float4*)(vvec + p * 16 + e);
                eqs[e]   = bcastf(t0.x); eqs[e+1] = bcastf(t0.y);
                eqs[e+2] = bcastf(t0.z); eqs[e+3] = bcastf(t0.w);
                v2h[e]   = bcastf(-2.f * tv.x); v2h[e+1] = bcastf(-2.f * tv.y);
                v2h[e+2] = bcastf(-2.f * tv.z); v2h[e+3] = bcastf(-2.f * tv.w);
            }
            #pragma unroll
            for (int i = 0; i < 4; i++) {      // 4 x 64 s within the half
                const int sl = lane + i * 64;
                u32x4 gA = sek[2 * p][sl];
                u32x4 gB = sek[2 * p + 1][sl];
                float a0 = 0.f, a1 = 0.f;      // 2 accumulate chains
                // pair: v0/q0 + v1/q1 = (v0*q1 + v1*q0) * rcp(q0*q1)
                #define PAIR(u, le, A)                                        \
                {                                                             \
                    float eklo = __uint_as_float((u) << 16);                  \
                    float ekhi = __uint_as_float((u) & 0xffff0000u);          \
                    float qa = __builtin_fmaf(eqs[le], eklo, 1.f);            \
                    float qb = __builtin_fmaf(eqs[(le) + 1], ekhi, 1.f);      \
                    float nm = __builtin_fmaf(v2h[le], qb, v2h[(le) + 1] * qa); \
                    A = __builtin_fmaf(nm, fast_rcp(qa * qb), A);             \
                }
                PAIR(gA[0], 0, a0) PAIR(gA[1], 2, a1)
                PAIR(gA[2], 4, a0) PAIR(gA[3], 6, a1)
                PAIR(gB[0], 8, a0) PAIR(gB[1], 10, a1)
                PAIR(gB[2], 12, a0) PAIR(gB[3], 14, a1)
                #undef PAIR
                sc[hs * 4 + i] += a0 + a1;
            }
        }
    }

    // ---- Phase 2: masks + per-wave softmax (registers only). ----
    float prob[SS / 64];
    {
        const float* mrow = mask + (size_t)l * SS;
        const float* kl   = klen + (size_t)b * SS;
        float mx = -1e30f;
        #pragma unroll
        for (int i = 0; i < SS / 64; i++) {
            int s = lane + i * 64;
            sc[i] += mrow[s] + kl[s];
            mx = fmaxf(mx, sc[i]);
        }
        #pragma unroll
        for (int off = 1; off < 64; off <<= 1) mx = fmaxf(mx, __shfl_xor(mx, off, 64));
        float ssum = 0.f;
        #pragma unroll
        for (int i = 0; i < SS / 64; i++) {
            prob[i] = __expf(sc[i] - mx);
            ssum += prob[i];
        }
        #pragma unroll
        for (int off = 1; off < 64; off <<= 1) ssum += __shfl_xor(ssum, off, 64);
        float inv = fast_rcp(ssum);
        #pragma unroll
        for (int i = 0; i < SS / 64; i++) prob[i] *= inv;
    }

    __syncthreads();   // all sek reads done -> safe to alias with sAb

    // write probs -> sAb row w (bf16, chunk-swizzled; verified 0-conflict)
    {
        const int fsw = (w * 5) & 7;
        #pragma unroll
        for (int i = 0; i < SS / 64; i++) {
            int col = lane + i * 64;
            int pos = (((col >> 3) ^ fsw) << 3) | (col & 7);
            sAb[w * SS + pos] = f2bf(prob[i]);
        }
    }
    __syncthreads();   // sAb handoff

    // ---- Phase 3: PV via MFMA; B-frag = 1 coalesced bf16x8 (frag image). --
    // A = 4x512 probs (rows 4..15 zero); wave w owns d-chunk w*16..+15.
    const int am  = lane & 15;
    const int qd  = lane >> 4;
    const int dof = w * 16 + am;
    const int fam = (am * 5) & 7;              // A-row swizzle (matches write)
    const bf16x8* vf =
        ws_vtf + ((size_t)((b * HH + h) * 4 + w) * 16) * 64 + lane;
    f32x4 acc = {0.f, 0.f, 0.f, 0.f};
    bf16x8 bcur = vf[0];
    for (int c = 0; c < SS / 32; c++) {
        bf16x8 bnxt = bcur;
        if (c < SS / 32 - 1) bnxt = vf[(c + 1) * 64];
        bf16x8 af = {0, 0, 0, 0, 0, 0, 0, 0};
        if (am < 4)
            af = *(const bf16x8*)&sAb[am * SS + ((((c * 4 + qd) ^ fam)) << 3)];
        acc = __builtin_amdgcn_mfma_f32_16x16x32_bf16(af, bcur, acc, 0, 0, 0);
        bcur = bnxt;
    }
    // C layout: col = lane&15 (d), row = qd*4 + reg; valid rows 0..3 -> qd==0
    if (qd == 0) {
        float* orow = out + (((size_t)b * LL + l0) * HH + h) * DD + dof;
        #pragma unroll
        for (int r = 0; r < 4; r++)
            orow[(size_t)r * (HH * DD)] = acc[r];
    }
}

extern "C" void kernel_launch(void* const* d_in, const int* in_sizes, int n_in,
                              void* d_out, int out_size, void* d_ws, size_t ws_size,
                              hipStream_t stream) {
    const float* q    = (const float*)d_in[0];
    const float* k    = (const float*)d_in[1];
    const float* vals = (const float*)d_in[2];
    const float* vvec = (const float*)d_in[3];
    const float* mask = (const float*)d_in[4];
    const float* klen = (const float*)d_in[5];
    float* outp = (float*)d_out;

    float* ws = (float*)d_ws;
    prep_kernel<<<dim3(640), dim3(256), 0, stream>>>(q, k, vals, ws);

    const u32x4* ws_ekb = (const u32x4*)((char*)d_ws + WS_EK_OFF);
    const float* ws_eqf = (const float*)((char*)d_ws + WS_EQ_OFF);
    const bf16x8* ws_vtf = (const bf16x8*)((char*)d_ws + WS_VT_OFF);
    addattn_kernel<<<dim3(BB * HH * (LL / 4)), dim3(256), 0, stream>>>(
        ws_ekb, ws_eqf, ws_vtf, vvec, mask, klen, outp);
}